// Round 2
// baseline (63.645 us; speedup 1.0000x reference)
//
#include <hip/hip_runtime.h>

// TimeNormalization: EMA scan over time + normalization.
//   s_t = 0.1*[x, x^2] + 0.9*s_{t-1}   (per (b,f), scan over t)
//   x_norm = (x - m) / sqrt(v - m^2 + 1e-3)
// Outputs concatenated: x_norm [B,T,F] then final_state [2,B,F].
//
// Chunked-scan parallelization: 0.9^128 ~ 1.4e-6, so each chunk warms its
// state over a KH=128 halo (chunk 0 uses the exact init state). R1 evidence:
// latency-bound (occ 18%, VALUBusy 16%, HBM 32%), and L3 retains x so halo
// re-reads are cheap -> CL=128 (32 chunks, 1024 blocks, 16 waves/CU).

namespace {
constexpr int Bc = 16, Tc = 4096, Fc = 512;
constexpr int CL = 128;          // chunk length
constexpr int KH = 128;          // halo (0.9^128 ~ 1.4e-6; accuracy-critical, don't shrink)
constexpr int NCHUNK = Tc / CL;  // 32
constexpr float ALPHA = 0.1f;
constexpr float OMA = 0.9f;
constexpr float EPS = 1e-3f;
}

__global__ __launch_bounds__(256) void tn_kernel(const float* __restrict__ x,
                                                 const float* __restrict__ state,
                                                 float* __restrict__ out) {
    const int bid = blockIdx.x;            // grid = B * NCHUNK * 2 = 1024
    const int fh = bid & 1;                // which half of F
    const int chunk = (bid >> 1) & (NCHUNK - 1);
    const int b = bid >> 6;                // 2*NCHUNK = 64
    const int f = fh * 256 + threadIdx.x;  // feature index (coalesced across lanes)
    const int t0 = chunk * CL;

    const size_t base = ((size_t)b * Tc + t0) * Fc + f;
    const float* xp = x + base;

    float s_m, s_v;
    if (chunk == 0) {
        // exact initial state: state[0,b,f] (mean), state[1,b,f] (mean-square)
        s_m = state[b * Fc + f];
        s_v = state[Bc * Fc + b * Fc + f];
    } else {
        // halo warm-up; truncated history contributes <= 0.9^KH
        s_m = 0.f;
        s_v = 0.f;
        const float* wp = xp - (size_t)KH * Fc;
#pragma unroll 16
        for (int i = 0; i < KH; ++i) {
            float xv = wp[(size_t)i * Fc];
            float px = ALPHA * xv;
            s_m = fmaf(OMA, s_m, px);
            s_v = fmaf(OMA, s_v, px * xv);
        }
    }

    float* op = out + base;
#pragma unroll 16
    for (int i = 0; i < CL; ++i) {
        float xv = xp[(size_t)i * Fc];
        float px = ALPHA * xv;
        s_m = fmaf(OMA, s_m, px);
        s_v = fmaf(OMA, s_v, px * xv);
        float var = fmaf(-s_m, s_m, s_v);          // v - m^2  (>= 0 analytically)
        float r = (xv - s_m) * rsqrtf(var + EPS);
        __builtin_nontemporal_store(r, &op[(size_t)i * Fc]);  // write-once stream
    }

    if (chunk == NCHUNK - 1) {
        // final_state [2,B,F] appended after x_norm
        const size_t so = (size_t)Bc * Tc * Fc;
        out[so + (size_t)b * Fc + f] = s_m;
        out[so + (size_t)Bc * Fc + (size_t)b * Fc + f] = s_v;
    }
}

extern "C" void kernel_launch(void* const* d_in, const int* in_sizes, int n_in,
                              void* d_out, int out_size, void* d_ws, size_t ws_size,
                              hipStream_t stream) {
    const float* x = (const float*)d_in[0];      // [B,T,F] f32
    const float* st = (const float*)d_in[1];     // [2,B,F] f32
    float* out = (float*)d_out;                  // x_norm + final_state

    dim3 grid(Bc * NCHUNK * 2);
    dim3 block(256);
    tn_kernel<<<grid, block, 0, stream>>>(x, st, out);
}